// Round 1
// baseline (135.475 us; speedup 1.0000x reference)
//
#include <hip/hip_runtime.h>

// FWHT of 2^24 float32, output scaled by 1/2^24.
// Two passes over global memory:
//   Pass 1: bits 0-13 (contiguous 16K chunks, 64 KB LDS, reg-blocked 5+5+4)
//   Pass 2: bits 14-23 over the (r=1024, c=16384) view.
//     v1: 16-col tiles -> 64 B segments  -> 2.85 TB/s
//     v2: 32-col tiles -> 128 B segments -> ~3.3 TB/s
//     v3 (this): 64-col tiles, 1024 threads/block, 128 KB LDS ->
//         256 B segments on every global load/store. Exchange in two
//         512-row chunks (3 barriers, same structure as v2). In-place,
//         applies 1/N.

#define N_LOG2 24
#define CHUNK_LOG2 14           // pass-1 chunk = 16384 elements = 64 KB LDS
#define CHUNK (1 << CHUNK_LOG2)

// Pass-1 LDS swizzle: flips addr bits 2-4 with (row ^ row>>2)&7, row = e>>5.
// All pass-1 LDS phases land at <=2 lanes/bank (free per m136); keeps 16 B
// alignment for float4 stores.
static __device__ __forceinline__ int swz(int e) {
  return e ^ ((((e >> 5) ^ (e >> 7)) & 7) << 2);
}

static __device__ __forceinline__ void fwht32(float* v) {
#pragma unroll
  for (int h = 1; h < 32; h <<= 1) {
#pragma unroll
    for (int g = 0; g < 32; g += 2 * h) {
#pragma unroll
      for (int k = 0; k < h; ++k) {
        float a = v[g + k], b = v[g + k + h];
        v[g + k] = a + b;
        v[g + k + h] = a - b;
      }
    }
  }
}

static __device__ __forceinline__ void fwht16(float* v) {
#pragma unroll
  for (int h = 1; h < 16; h <<= 1) {
#pragma unroll
    for (int g = 0; g < 16; g += 2 * h) {
#pragma unroll
      for (int k = 0; k < h; ++k) {
        float a = v[g + k], b = v[g + k + h];
        v[g + k] = a + b;
        v[g + k + h] = a - b;
      }
    }
  }
}

// Pass 1: per-block contiguous chunk of 16384 floats; stages over bits 0-13.
// (unchanged from previous round)
__global__ __launch_bounds__(512) void fwht_pass1(const float* __restrict__ in,
                                                  float* __restrict__ out) {
  __shared__ float lds[CHUNK];
  const int t = threadIdx.x;                 // [0, 512)
  const int base = (int)blockIdx.x << CHUNK_LOG2;
  float v[32];

  // Group 0: thread owns contiguous e = 32t .. 32t+31 (bits 0-4).
  const float4* g4 = reinterpret_cast<const float4*>(in + base) + t * 8;
#pragma unroll
  for (int q = 0; q < 8; ++q) {
    float4 f = g4[q];
    v[4 * q + 0] = f.x; v[4 * q + 1] = f.y;
    v[4 * q + 2] = f.z; v[4 * q + 3] = f.w;
  }
  fwht32(v);  // bits 0-4
#pragma unroll
  for (int q = 0; q < 8; ++q) {
    int e = t * 32 + q * 4;
    *reinterpret_cast<float4*>(&lds[swz(e)]) =
        make_float4(v[4 * q], v[4 * q + 1], v[4 * q + 2], v[4 * q + 3]);
  }
  __syncthreads();

  // Group 1: thread owns e = lo + (j<<5) + (hi<<10), j = 0..31 (bits 5-9).
  const int lo = t & 31, hi = t >> 5;        // hi in [0,16)
#pragma unroll
  for (int j = 0; j < 32; ++j) v[j] = lds[swz(lo + (j << 5) + (hi << 10))];
  fwht32(v);  // bits 5-9
#pragma unroll
  for (int j = 0; j < 32; ++j) lds[swz(lo + (j << 5) + (hi << 10))] = v[j];
  __syncthreads();

  // Group 2: thread owns e = f + (jr<<10) for f = t, t+512 (bits 10-13).
#pragma unroll
  for (int b = 0; b < 2; ++b) {
    int f = t + (b << 9);
#pragma unroll
    for (int jr = 0; jr < 16; ++jr) v[b * 16 + jr] = lds[swz(f + (jr << 10))];
  }
  fwht16(v);
  fwht16(v + 16);
#pragma unroll
  for (int b = 0; b < 2; ++b) {
    int f = t + (b << 9);
#pragma unroll
    for (int jr = 0; jr < 16; ++jr) out[base + f + (jr << 10)] = v[b * 16 + jr];
  }
}

// Pass 2 v3: view i = r*16384 + c, r in [0,1024), c in [0,16384).
// Block owns a 1024-row x 64-col tile (grid 256, 1024 threads). Thread t:
// c = t&63, rgrp = t>>6 in [0,16). Per global load/store instruction a wave
// (rgrp fixed, c = 0..63) touches one row x 256 B contiguous — double v2's
// 128 B segments.
// Phase A: v0[j] = row rgrp*32+j (rows 0-511), v1[j] = row 512+rgrp*32+j
//   -> fwht32 = bits 14-18 (low 5 row bits).
// Exchange via 128 KB LDS (512 rows x 64 cols) in two chunks; phase B owns
//   u0[j] = row rgrp+32j, u1[j] = row rgrp+16+32j -> fwht32 = bits 19-23.
// Every LDS addr = row*64 + c -> bank = c&31 -> 2 lanes/bank (free).
// In-place safe: all global loads drained at first barrier (syncthreads
// implies vmcnt(0)); stores follow last barrier; blocks own disjoint cols.
__global__ __launch_bounds__(1024, 4) void fwht_pass2(float* __restrict__ io) {
  __shared__ float lds[512 * 64];            // 32768 floats = 128 KB
  const int t = threadIdx.x;                 // [0, 1024)
  const int c = t & 63, rgrp = t >> 6;       // rgrp in [0,16)
  const int cbase = (int)blockIdx.x * 64;
  float v0[32], v1[32], u0[32], u1[32];

  // A: v0[j] = elem(r = rgrp*32 + j), v1[j] = elem(r = (rgrp+16)*32 + j).
#pragma unroll
  for (int j = 0; j < 32; ++j)
    v0[j] = io[(rgrp * 32 + j) * CHUNK + cbase + c];
#pragma unroll
  for (int j = 0; j < 32; ++j)
    v1[j] = io[((rgrp + 16) * 32 + j) * CHUNK + cbase + c];
  fwht32(v0);  // bits 14-18 (rows 0-511 group)
  fwht32(v1);  // bits 14-18 (rows 512-1023 group)

  // Chunk 0: rows [0,512) == all of v0. LDS idx = r*64 + c.
#pragma unroll
  for (int j = 0; j < 32; ++j)
    lds[(rgrp * 32 + j) * 64 + c] = v0[j];
  __syncthreads();
  // B wants u0[j] = row rgrp + 32j, u1[j] = row rgrp+16 + 32j.
  // Chunk 0 supplies j in [0,16).
#pragma unroll
  for (int j = 0; j < 16; ++j)
    u0[j] = lds[(rgrp + 32 * j) * 64 + c];
#pragma unroll
  for (int j = 0; j < 16; ++j)
    u1[j] = lds[(rgrp + 16 + 32 * j) * 64 + c];
  __syncthreads();

  // Chunk 1: rows [512,1024) == all of v1. LDS idx = (r-512)*64 + c.
#pragma unroll
  for (int j = 0; j < 32; ++j)
    lds[(rgrp * 32 + j) * 64 + c] = v1[j];
  __syncthreads();
  // Chunk 1 supplies j in [16,32): r-512 = rgrp(+16) + 32(j-16).
#pragma unroll
  for (int j = 16; j < 32; ++j)
    u0[j] = lds[(rgrp + 32 * (j - 16)) * 64 + c];
#pragma unroll
  for (int j = 16; j < 32; ++j)
    u1[j] = lds[(rgrp + 16 + 32 * (j - 16)) * 64 + c];

  fwht32(u0);  // bits 19-23
  fwht32(u1);
  const float s = 1.0f / 16777216.0f;
#pragma unroll
  for (int j = 0; j < 32; ++j)
    io[(rgrp + 32 * j) * CHUNK + cbase + c] = u0[j] * s;
#pragma unroll
  for (int j = 0; j < 32; ++j)
    io[(rgrp + 16 + 32 * j) * CHUNK + cbase + c] = u1[j] * s;
}

extern "C" void kernel_launch(void* const* d_in, const int* in_sizes, int n_in,
                              void* d_out, int out_size, void* d_ws, size_t ws_size,
                              hipStream_t stream) {
  const float* in = (const float*)d_in[0];
  float* out = (float*)d_out;
  // N = 2^24: pass 1 -> d_out, pass 2 in-place on d_out.
  fwht_pass1<<<1024, 512, 0, stream>>>(in, out);
  fwht_pass2<<<256, 1024, 0, stream>>>(out);
}

// Round 2
// 134.181 us; speedup vs baseline: 1.0096x; 1.0096x over previous
//
#include <hip/hip_runtime.h>

// FWHT of 2^24 float32, output scaled by 1/2^24.
// Two passes over global memory:
//   Pass 1: bits 0-13 (contiguous 16K chunks, 64 KB LDS, reg-blocked 5+5+4)
//   Pass 2: bits 14-23 over the (r=1024, c=16384) view.
//     v1: 16-col tiles -> 64 B segments  -> 2.85 TB/s
//     v2: 32-col tiles -> 128 B segments -> ~3.3 TB/s
//     v3: 64-col tiles (256 B segments)  -> ~3.3 TB/s (NULL: segment width
//         >=128 B is not the limiter)
//     v4 (this): v3 + XCD-gang column mapping. Blocks land on XCDs
//         round-robin (b%8); remap block->column-window with
//         cbase = ((b&7)*32 + (b>>3))*64 so the 32 blocks co-resident on
//         one XCD own 32 ADJACENT 64-col windows = 8 KB contiguous per row.
//         Their j-loops run in near-lockstep, so per row the XCD touches
//         8 KB contiguous (full DRAM pages, one L2) instead of 32 scattered
//         256 B shards at 64 KB stride. Bijective on [0,256) -> correctness
//         unchanged. In-place, applies 1/N.

#define N_LOG2 24
#define CHUNK_LOG2 14           // pass-1 chunk = 16384 elements = 64 KB LDS
#define CHUNK (1 << CHUNK_LOG2)

// Pass-1 LDS swizzle: flips addr bits 2-4 with (row ^ row>>2)&7, row = e>>5.
// All pass-1 LDS phases land at <=2 lanes/bank (free per m136); keeps 16 B
// alignment for float4 stores.
static __device__ __forceinline__ int swz(int e) {
  return e ^ ((((e >> 5) ^ (e >> 7)) & 7) << 2);
}

static __device__ __forceinline__ void fwht32(float* v) {
#pragma unroll
  for (int h = 1; h < 32; h <<= 1) {
#pragma unroll
    for (int g = 0; g < 32; g += 2 * h) {
#pragma unroll
      for (int k = 0; k < h; ++k) {
        float a = v[g + k], b = v[g + k + h];
        v[g + k] = a + b;
        v[g + k + h] = a - b;
      }
    }
  }
}

static __device__ __forceinline__ void fwht16(float* v) {
#pragma unroll
  for (int h = 1; h < 16; h <<= 1) {
#pragma unroll
    for (int g = 0; g < 16; g += 2 * h) {
#pragma unroll
      for (int k = 0; k < h; ++k) {
        float a = v[g + k], b = v[g + k + h];
        v[g + k] = a + b;
        v[g + k + h] = a - b;
      }
    }
  }
}

// Pass 1: per-block contiguous chunk of 16384 floats; stages over bits 0-13.
// (unchanged)
__global__ __launch_bounds__(512) void fwht_pass1(const float* __restrict__ in,
                                                  float* __restrict__ out) {
  __shared__ float lds[CHUNK];
  const int t = threadIdx.x;                 // [0, 512)
  const int base = (int)blockIdx.x << CHUNK_LOG2;
  float v[32];

  // Group 0: thread owns contiguous e = 32t .. 32t+31 (bits 0-4).
  const float4* g4 = reinterpret_cast<const float4*>(in + base) + t * 8;
#pragma unroll
  for (int q = 0; q < 8; ++q) {
    float4 f = g4[q];
    v[4 * q + 0] = f.x; v[4 * q + 1] = f.y;
    v[4 * q + 2] = f.z; v[4 * q + 3] = f.w;
  }
  fwht32(v);  // bits 0-4
#pragma unroll
  for (int q = 0; q < 8; ++q) {
    int e = t * 32 + q * 4;
    *reinterpret_cast<float4*>(&lds[swz(e)]) =
        make_float4(v[4 * q], v[4 * q + 1], v[4 * q + 2], v[4 * q + 3]);
  }
  __syncthreads();

  // Group 1: thread owns e = lo + (j<<5) + (hi<<10), j = 0..31 (bits 5-9).
  const int lo = t & 31, hi = t >> 5;        // hi in [0,16)
#pragma unroll
  for (int j = 0; j < 32; ++j) v[j] = lds[swz(lo + (j << 5) + (hi << 10))];
  fwht32(v);  // bits 5-9
#pragma unroll
  for (int j = 0; j < 32; ++j) lds[swz(lo + (j << 5) + (hi << 10))] = v[j];
  __syncthreads();

  // Group 2: thread owns e = f + (jr<<10) for f = t, t+512 (bits 10-13).
#pragma unroll
  for (int b = 0; b < 2; ++b) {
    int f = t + (b << 9);
#pragma unroll
    for (int jr = 0; jr < 16; ++jr) v[b * 16 + jr] = lds[swz(f + (jr << 10))];
  }
  fwht16(v);
  fwht16(v + 16);
#pragma unroll
  for (int b = 0; b < 2; ++b) {
    int f = t + (b << 9);
#pragma unroll
    for (int jr = 0; jr < 16; ++jr) out[base + f + (jr << 10)] = v[b * 16 + jr];
  }
}

// Pass 2 v4: view i = r*16384 + c, r in [0,1024), c in [0,16384).
// Block owns a 1024-row x 64-col tile (grid 256, 1024 threads). Thread t:
// c = t&63, rgrp = t>>6 in [0,16). Per global load/store a wave touches one
// row x 256 B contiguous.
// NEW: column window chosen by XCD-gang mapping (see header comment):
//   cbase = ((b&7)*32 + (b>>3)) * 64
// so same-XCD blocks cover adjacent windows -> 8 KB contiguous per row
// per XCD when the co-resident blocks stream row j together.
// Phase A: v0[j] = row rgrp*32+j (rows 0-511), v1[j] = row 512+rgrp*32+j
//   -> fwht32 = bits 14-18. Exchange via 128 KB LDS in two 512-row chunks;
// phase B owns u0[j] = row rgrp+32j, u1[j] = row rgrp+16+32j -> bits 19-23.
// Every LDS addr = row*64 + c -> bank = c&31 -> 2 lanes/bank (free).
// In-place safe: all global loads drained at first barrier; stores follow
// last barrier; blocks own disjoint cols.
__global__ __launch_bounds__(1024, 4) void fwht_pass2(float* __restrict__ io) {
  __shared__ float lds[512 * 64];            // 32768 floats = 128 KB
  const int t = threadIdx.x;                 // [0, 1024)
  const int c = t & 63, rgrp = t >> 6;       // rgrp in [0,16)
  const int b = (int)blockIdx.x;             // [0, 256)
  const int cbase = (((b & 7) * 32) + (b >> 3)) * 64;  // XCD-gang window
  float v0[32], v1[32], u0[32], u1[32];

  // A: v0[j] = elem(r = rgrp*32 + j), v1[j] = elem(r = (rgrp+16)*32 + j).
#pragma unroll
  for (int j = 0; j < 32; ++j)
    v0[j] = io[(rgrp * 32 + j) * CHUNK + cbase + c];
#pragma unroll
  for (int j = 0; j < 32; ++j)
    v1[j] = io[((rgrp + 16) * 32 + j) * CHUNK + cbase + c];
  fwht32(v0);  // bits 14-18 (rows 0-511 group)
  fwht32(v1);  // bits 14-18 (rows 512-1023 group)

  // Chunk 0: rows [0,512) == all of v0. LDS idx = r*64 + c.
#pragma unroll
  for (int j = 0; j < 32; ++j)
    lds[(rgrp * 32 + j) * 64 + c] = v0[j];
  __syncthreads();
  // B wants u0[j] = row rgrp + 32j, u1[j] = row rgrp+16 + 32j.
  // Chunk 0 supplies j in [0,16).
#pragma unroll
  for (int j = 0; j < 16; ++j)
    u0[j] = lds[(rgrp + 32 * j) * 64 + c];
#pragma unroll
  for (int j = 0; j < 16; ++j)
    u1[j] = lds[(rgrp + 16 + 32 * j) * 64 + c];
  __syncthreads();

  // Chunk 1: rows [512,1024) == all of v1. LDS idx = (r-512)*64 + c.
#pragma unroll
  for (int j = 0; j < 32; ++j)
    lds[(rgrp * 32 + j) * 64 + c] = v1[j];
  __syncthreads();
  // Chunk 1 supplies j in [16,32): r-512 = rgrp(+16) + 32(j-16).
#pragma unroll
  for (int j = 16; j < 32; ++j)
    u0[j] = lds[(rgrp + 32 * (j - 16)) * 64 + c];
#pragma unroll
  for (int j = 16; j < 32; ++j)
    u1[j] = lds[(rgrp + 16 + 32 * (j - 16)) * 64 + c];

  fwht32(u0);  // bits 19-23
  fwht32(u1);
  const float s = 1.0f / 16777216.0f;
#pragma unroll
  for (int j = 0; j < 32; ++j)
    io[(rgrp + 32 * j) * CHUNK + cbase + c] = u0[j] * s;
#pragma unroll
  for (int j = 0; j < 32; ++j)
    io[(rgrp + 16 + 32 * j) * CHUNK + cbase + c] = u1[j] * s;
}

extern "C" void kernel_launch(void* const* d_in, const int* in_sizes, int n_in,
                              void* d_out, int out_size, void* d_ws, size_t ws_size,
                              hipStream_t stream) {
  const float* in = (const float*)d_in[0];
  float* out = (float*)d_out;
  // N = 2^24: pass 1 -> d_out, pass 2 in-place on d_out.
  fwht_pass1<<<1024, 512, 0, stream>>>(in, out);
  fwht_pass2<<<256, 1024, 0, stream>>>(out);
}